// Round 16
// baseline (77.322 us; speedup 1.0000x reference)
//
#include <hip/hip_runtime.h>
#include <math.h>

// TDVP_V2: BATCH=16384 chains, N=64 sites, D=4, DIN=DOUT=2.
// v16 = v15 (best, JSON 77.0) + double-buffered LDS reads in the two
// serial scan loops. Those loops are `#pragma unroll 1` (divergent trip
// count: t<s / t>s) so the compiler cannot software-pipeline them; each of
// the ~8 wave-serialized steps paid ~100+ cyc of dependent ds_read latency
// (16 b32 reads issued at use). Now row t+1 is prefetched into 16 named
// scalars (no indexed arrays in divergent code — v4 spill lesson) while
// step t computes. Register budget in phase 2 ~190 < 256; occupancy is
// grid-capped at 2 waves/SIMD so the extra VGPRs cost nothing.
// Everything else is v15 verbatim:
//   bb = tid&31 (32 chains/block), s = tid>>5 (segment 0..7).
//   grid = 512 x 256 -> 2 blocks/CU. LDS 57.3 KB: sP 16 + sXY 16.6 +
//   sA 8 + sB 16. A/B broadcast ds_reads; M[0..7] register-cached;
//   rsq normalizations; coalesced x/y through sXY.

#define EPS 1e-6f
#define RSQ(x) __builtin_amdgcn_rsqf((x) + 1e-30f)

__global__ __launch_bounds__(256)
void tdvp_kernel(const float* __restrict__ x,
                 const float* __restrict__ A,
                 const float* __restrict__ Bw,
                 const float* __restrict__ scale,
                 float* __restrict__ y)
{
    __shared__ float  sP[8 * 16 * 32];   // [t][e][bb]      16 KB
    __shared__ float  sXY[32 * 130];     // [chain][2*site] 16.6 KB
    __shared__ float4 sA[64 * 8];        // A[site][8]       8 KB
    __shared__ float4 sB[64 * 16];       // B[site][16]     16 KB

    const int tid = threadIdx.x;
    const int bb  = tid & 31;
    const int s   = tid >> 5;            // 0..7

    // ---- stage x (coalesced) + A + B into LDS ----------------------------
    {
        const float4* xg = (const float4*)x + (size_t)blockIdx.x * 1024;
        #pragma unroll
        for (int it = 0; it < 4; ++it) {
            const int g = it * 256 + tid;
            const float4 v = xg[g];
            const int c = g >> 5, f = (g & 31) * 4;
            *(float2*)&sXY[c * 130 + f]     = make_float2(v.x, v.y);
            *(float2*)&sXY[c * 130 + f + 2] = make_float2(v.z, v.w);
        }
        const float4* Ag = (const float4*)A;     // 512 float4
        #pragma unroll
        for (int it = 0; it < 2; ++it)
            sA[it * 256 + tid] = Ag[it * 256 + tid];
        const float4* Bg = (const float4*)Bw;    // 1024 float4
        #pragma unroll
        for (int it = 0; it < 4; ++it)
            sB[it * 256 + tid] = Bg[it * 256 + tid];
    }
    __syncthreads();

    // ---- my 8 sites from LDS, normalized --------------------------------
    const int n0 = s * 8;
    float xa[8], xc[8];
    #pragma unroll
    for (int k = 0; k < 8; ++k) {
        const float2 v = *(const float2*)&sXY[bb * 130 + s * 16 + 2 * k];
        const float inr = RSQ(v.x * v.x + v.y * v.y);
        xa[k] = v.x * inr; xc[k] = v.y * inr;
    }

    // ---- build all 8 M matrices ONCE into registers (A from LDS) ---------
    float M[8][16];
    #pragma unroll
    for (int k = 0; k < 8; ++k) {
        const float4* Aq = &sA[(n0 + k) * 8];
        #pragma unroll
        for (int t = 0; t < 8; ++t) {
            const float4 q = Aq[t];
            M[k][2*t]     = fmaf(xc[k], q.y, xa[k] * q.x);
            M[k][2*t + 1] = fmaf(xc[k], q.w, xa[k] * q.z);
        }
    }

    // ---- phase 1: segment product P = M[0]..M[7] (normalized) -> sP ------
    {
        float P[16];
        #pragma unroll
        for (int e = 0; e < 16; ++e) P[e] = M[0][e];
        #pragma unroll
        for (int k = 1; k < 8; ++k) {
            float Pn[16];
            #pragma unroll
            for (int i = 0; i < 4; ++i) {
                #pragma unroll
                for (int j = 0; j < 4; ++j) {
                    float acc = P[i*4] * M[k][j];
                    acc = fmaf(P[i*4+1], M[k][4+j],  acc);
                    acc = fmaf(P[i*4+2], M[k][8+j],  acc);
                    acc = fmaf(P[i*4+3], M[k][12+j], acc);
                    Pn[i*4+j] = acc;
                }
            }
            #pragma unroll
            for (int e = 0; e < 16; ++e) P[e] = Pn[e];
        }
        float ss = 0.f;
        #pragma unroll
        for (int e = 0; e < 16; ++e) ss = fmaf(P[e], P[e], ss);
        const float rn = RSQ(ss);
        #pragma unroll
        for (int e = 0; e < 16; ++e)
            sP[s * 512 + e * 32 + bb] = P[e] * rn;
    }
    __syncthreads();

    // ---- phase 2: prefix / suffix scans with double-buffered reads -------
    float v0 = 1.f, v1 = 0.f, v2 = 0.f, v3 = 0.f;
    {
        // prefetch row 0 (valid memory even if s==0; only used when s>0)
        const float* pp = &sP[bb];
        float n0_ = pp[0],    n1_ = pp[32],   n2_ = pp[64],   n3_ = pp[96];
        float n4_ = pp[128],  n5_ = pp[160],  n6_ = pp[192],  n7_ = pp[224];
        float n8_ = pp[256],  n9_ = pp[288],  n10_ = pp[320], n11_ = pp[352];
        float n12_ = pp[384], n13_ = pp[416], n14_ = pp[448], n15_ = pp[480];
        #pragma unroll 1
        for (int t = 0; t < s; ++t) {
            const float p0 = n0_,  p1 = n1_,  p2 = n2_,  p3 = n3_;
            const float p4 = n4_,  p5 = n5_,  p6 = n6_,  p7 = n7_;
            const float p8 = n8_,  p9 = n9_,  p10 = n10_, p11 = n11_;
            const float p12 = n12_, p13 = n13_, p14 = n14_, p15 = n15_;
            if (t + 1 < s) {            // prefetch next row during compute
                const float* np = &sP[(t + 1) * 512 + bb];
                n0_ = np[0];    n1_ = np[32];   n2_ = np[64];   n3_ = np[96];
                n4_ = np[128];  n5_ = np[160];  n6_ = np[192];  n7_ = np[224];
                n8_ = np[256];  n9_ = np[288];  n10_ = np[320]; n11_ = np[352];
                n12_ = np[384]; n13_ = np[416]; n14_ = np[448]; n15_ = np[480];
            }
            const float w0 = v0*p0 + v1*p4 + v2*p8  + v3*p12;
            const float w1 = v0*p1 + v1*p5 + v2*p9  + v3*p13;
            const float w2 = v0*p2 + v1*p6 + v2*p10 + v3*p14;
            const float w3 = v0*p3 + v1*p7 + v2*p11 + v3*p15;
            const float rn = RSQ(w0*w0 + w1*w1 + w2*w2 + w3*w3);
            v0 = w0*rn; v1 = w1*rn; v2 = w2*rn; v3 = w3*rn;
        }
    }
    float u0 = 1.f, u1 = 0.f, u2 = 0.f, u3 = 0.f;
    {
        // prefetch row 7 (only used when s<7)
        const float* pp = &sP[7 * 512 + bb];
        float n0_ = pp[0],    n1_ = pp[32],   n2_ = pp[64],   n3_ = pp[96];
        float n4_ = pp[128],  n5_ = pp[160],  n6_ = pp[192],  n7_ = pp[224];
        float n8_ = pp[256],  n9_ = pp[288],  n10_ = pp[320], n11_ = pp[352];
        float n12_ = pp[384], n13_ = pp[416], n14_ = pp[448], n15_ = pp[480];
        #pragma unroll 1
        for (int t = 7; t > s; --t) {
            const float p0 = n0_,  p1 = n1_,  p2 = n2_,  p3 = n3_;
            const float p4 = n4_,  p5 = n5_,  p6 = n6_,  p7 = n7_;
            const float p8 = n8_,  p9 = n9_,  p10 = n10_, p11 = n11_;
            const float p12 = n12_, p13 = n13_, p14 = n14_, p15 = n15_;
            if (t - 1 > s) {            // prefetch next row during compute
                const float* np = &sP[(t - 1) * 512 + bb];
                n0_ = np[0];    n1_ = np[32];   n2_ = np[64];   n3_ = np[96];
                n4_ = np[128];  n5_ = np[160];  n6_ = np[192];  n7_ = np[224];
                n8_ = np[256];  n9_ = np[288];  n10_ = np[320]; n11_ = np[352];
                n12_ = np[384]; n13_ = np[416]; n14_ = np[448]; n15_ = np[480];
            }
            const float w0 = p0*u0  + p1*u1  + p2*u2  + p3*u3;
            const float w1 = p4*u0  + p5*u1  + p6*u2  + p7*u3;
            const float w2 = p8*u0  + p9*u1  + p10*u2 + p11*u3;
            const float w3 = p12*u0 + p13*u1 + p14*u2 + p15*u3;
            const float rn = RSQ(w0*w0 + w1*w1 + w2*w2 + w3*w3);
            u0 = w0*rn; u1 = w1*rn; u2 = w2*rn; u3 = w3*rn;
        }
    }

    // ---- phase 3a: forward walk, store vl per site (cached M) ------------
    float vlA[8], vlB[8], vlC[8], vlD[8];
    {
        float a0 = v0, a1 = v1, a2 = v2, a3 = v3;
        #pragma unroll
        for (int k = 0; k < 8; ++k) {
            vlA[k] = a0; vlB[k] = a1; vlC[k] = a2; vlD[k] = a3;
            if (k == 7) break;
            const float t0 = a0*M[k][0] + a1*M[k][4] + a2*M[k][8]  + a3*M[k][12];
            const float t1 = a0*M[k][1] + a1*M[k][5] + a2*M[k][9]  + a3*M[k][13];
            const float t2 = a0*M[k][2] + a1*M[k][6] + a2*M[k][10] + a3*M[k][14];
            const float t3 = a0*M[k][3] + a1*M[k][7] + a2*M[k][11] + a3*M[k][15];
            a0 = t0; a1 = t1; a2 = t2; a3 = t3;
        }
    }

    // ---- phase 3b: backward walk + fused epilogue (B from LDS) -> sXY ----
    const float sc = scale[0];
    #pragma unroll
    for (int kk = 7; kk >= 0; --kk) {
        const int n = n0 + kk;

        const float arn = RSQ(u0*u0 + u1*u1 + u2*u2 + u3*u3);
        float aa0 = u0*arn, aa1 = u1*arn, aa2 = u2*arn, aa3 = u3*arn;
        if (n == 63) { aa0 = 1.f; aa1 = aa2 = aa3 = 0.f; }

        const float wn = RSQ(vlA[kk]*vlA[kk] + vlB[kk]*vlB[kk] +
                             vlC[kk]*vlC[kk] + vlD[kk]*vlD[kk]);
        float vv0 = vlA[kk]*wn, vv1 = vlB[kk]*wn, vv2 = vlC[kk]*wn, vv3 = vlD[kk]*wn;
        if (n == 0) { vv0 = 1.f; vv1 = vv2 = vv3 = 0.f; }

        const float vv[4] = {vv0, vv1, vv2, vv3};
        const float aa[4] = {aa0, aa1, aa2, aa3};
        const float4* Bq = &sB[n * 16];
        float H00 = 0.f, H01 = 0.f, H10 = 0.f, H11 = 0.f;
        #pragma unroll
        for (int half = 0; half < 2; ++half) {       // 8 float4 live at a time
            float4 bq[8];
            #pragma unroll
            for (int t = 0; t < 8; ++t) bq[t] = Bq[half * 8 + t];
            #pragma unroll
            for (int i2 = 0; i2 < 2; ++i2) {
                const int i = half * 2 + i2;
                #pragma unroll
                for (int l = 0; l < 4; ++l) {
                    const float  c = vv[i] * aa[l];
                    const float4 q = bq[i2 * 4 + l];
                    H00 = fmaf(c, q.x, H00);
                    H01 = fmaf(c, q.y, H01);
                    H10 = fmaf(c, q.z, H10);
                    H11 = fmaf(c, q.w, H11);
                }
            }
        }
        const float rh = sc * RSQ(H00*H00 + H01*H01 + H10*H10 + H11*H11);
        H00 *= rh; H01 *= rh; H10 *= rh; H11 *= rh;
        if (__builtin_isnan(H00)) H00 = 0.f;
        if (__builtin_isnan(H01)) H01 = 0.f;
        if (__builtin_isnan(H10)) H10 = 0.f;
        if (__builtin_isnan(H11)) H11 = 0.f;
        H00 = fmaxf(H00, 0.f); H01 = fmaxf(H01, 0.f);
        H10 = fmaxf(H10, 0.f); H11 = fmaxf(H11, 0.f);

        float2 yo;
        yo.x = fmaf(H01, xc[kk], H00 * xa[kk]);
        yo.y = fmaf(H11, xc[kk], H10 * xa[kk]);
        *(float2*)&sXY[bb * 130 + 2 * n] = yo;

        if (kk > 0) {   // u <- M[kk].u  (raw suffix for site n-1)
            const float t0 = M[kk][0]*u0  + M[kk][1]*u1  + M[kk][2]*u2  + M[kk][3]*u3;
            const float t1 = M[kk][4]*u0  + M[kk][5]*u1  + M[kk][6]*u2  + M[kk][7]*u3;
            const float t2 = M[kk][8]*u0  + M[kk][9]*u1  + M[kk][10]*u2 + M[kk][11]*u3;
            const float t3 = M[kk][12]*u0 + M[kk][13]*u1 + M[kk][14]*u2 + M[kk][15]*u3;
            u0 = t0; u1 = t1; u2 = t2; u3 = t3;
        }
    }
    __syncthreads();

    // ---- y out: fully coalesced float4 stores ----------------------------
    {
        float4* yg = (float4*)y + (size_t)blockIdx.x * 1024;
        #pragma unroll
        for (int it = 0; it < 4; ++it) {
            const int g = it * 256 + tid;
            const int c = g >> 5, f = (g & 31) * 4;
            const float2 a = *(const float2*)&sXY[c * 130 + f];
            const float2 b = *(const float2*)&sXY[c * 130 + f + 2];
            yg[g] = make_float4(a.x, a.y, b.x, b.y);
        }
    }
}

extern "C" void kernel_launch(void* const* d_in, const int* in_sizes, int n_in,
                              void* d_out, int out_size, void* d_ws, size_t ws_size,
                              hipStream_t stream) {
    const float* x     = (const float*)d_in[0];
    const float* A     = (const float*)d_in[1];
    const float* B     = (const float*)d_in[2];
    const float* scale = (const float*)d_in[3];
    float* yp = (float*)d_out;
    const int batch  = in_sizes[0] / 128;    // 16384
    const int blocks = batch / 32;           // 512 blocks x 256 threads
    tdvp_kernel<<<blocks, 256, 0, stream>>>(x, A, B, scale, yp);
}

// Round 17
// 76.243 us; speedup vs baseline: 1.0142x; 1.0142x over previous
//
#include <hip/hip_runtime.h>
#include <math.h>

// TDVP_V2: BATCH=16384 chains, N=64 sites, D=4, DIN=DOUT=2.
// FINAL (v15, best measured: JSON 76.99 us, absmax 0.0039).
// Session ladder (JSON us): stub -> 178 (1 thread/chain) -> 103 (split
// scans+epilogue waves) -> 82.3 (segmented scan, coalesced x/y via LDS,
// M register-cache) -> 78.9 (A/B in LDS: broadcast ds_reads kill exposed
// VMEM latency) -> 77.0 (v_rsq_f32 for all ~45 normalizations).
// Measured-dead ends: >256-thread blocks never launch (v5/v6); 16-segment
// shapes lose to longer masked scans (v11/v14); 2 chains/thread spills at
// 256 VGPR (v12); scan prefetch neutral-negative (v16).
// Structure:
//   bb = tid&31 : chain-in-block (32 chains), s = tid>>5 : segment 0..7.
//   grid = 512 blocks x 256 threads -> 2 blocks/CU (grid-capped 2
//   waves/SIMD — raising it measured worse in both directions).
//   LDS 56.3 KB: sP (segment products) 16 + sXY (coalesced x/y) 16.6 +
//   sA 8 + sB 16. All per-lane LDS addrs == bb (mod 32) -> <=2-way = free.
// Phases: stage x/A/B -> build M[0..7] once into regs -> 8-site product
// P (Frobenius-normalized; scale cancels in H-norm) -> per-thread
// prefix/suffix vector scans -> forward walk (vl/site) -> backward walk
// fused with epilogue H=vl.B.ar, rsq-norm, nan->0, relu, y=H.xn -> sXY ->
// fully-coalesced float4 stores.

#define EPS 1e-6f
#define RSQ(x) __builtin_amdgcn_rsqf((x) + 1e-30f)

__global__ __launch_bounds__(256)
void tdvp_kernel(const float* __restrict__ x,
                 const float* __restrict__ A,
                 const float* __restrict__ Bw,
                 const float* __restrict__ scale,
                 float* __restrict__ y)
{
    __shared__ float  sP[8 * 16 * 32];   // [t][e][bb]      16 KB
    __shared__ float  sXY[32 * 130];     // [chain][2*site] 16.6 KB
    __shared__ float4 sA[64 * 8];        // A[site][8]       8 KB
    __shared__ float4 sB[64 * 16];       // B[site][16]     16 KB

    const int tid = threadIdx.x;
    const int bb  = tid & 31;
    const int s   = tid >> 5;            // 0..7

    // ---- stage x (coalesced) + A + B into LDS ----------------------------
    {
        const float4* xg = (const float4*)x + (size_t)blockIdx.x * 1024;
        #pragma unroll
        for (int it = 0; it < 4; ++it) {
            const int g = it * 256 + tid;
            const float4 v = xg[g];
            const int c = g >> 5, f = (g & 31) * 4;
            *(float2*)&sXY[c * 130 + f]     = make_float2(v.x, v.y);
            *(float2*)&sXY[c * 130 + f + 2] = make_float2(v.z, v.w);
        }
        const float4* Ag = (const float4*)A;     // 512 float4
        #pragma unroll
        for (int it = 0; it < 2; ++it)
            sA[it * 256 + tid] = Ag[it * 256 + tid];
        const float4* Bg = (const float4*)Bw;    // 1024 float4
        #pragma unroll
        for (int it = 0; it < 4; ++it)
            sB[it * 256 + tid] = Bg[it * 256 + tid];
    }
    __syncthreads();

    // ---- my 8 sites from LDS, normalized --------------------------------
    const int n0 = s * 8;
    float xa[8], xc[8];
    #pragma unroll
    for (int k = 0; k < 8; ++k) {
        const float2 v = *(const float2*)&sXY[bb * 130 + s * 16 + 2 * k];
        const float inr = RSQ(v.x * v.x + v.y * v.y);
        xa[k] = v.x * inr; xc[k] = v.y * inr;
    }

    // ---- build all 8 M matrices ONCE into registers (A from LDS) ---------
    float M[8][16];
    #pragma unroll
    for (int k = 0; k < 8; ++k) {
        const float4* Aq = &sA[(n0 + k) * 8];
        #pragma unroll
        for (int t = 0; t < 8; ++t) {
            const float4 q = Aq[t];
            M[k][2*t]     = fmaf(xc[k], q.y, xa[k] * q.x);
            M[k][2*t + 1] = fmaf(xc[k], q.w, xa[k] * q.z);
        }
    }

    // ---- phase 1: segment product P = M[0]..M[7] (normalized) -> sP ------
    {
        float P[16];
        #pragma unroll
        for (int e = 0; e < 16; ++e) P[e] = M[0][e];
        #pragma unroll
        for (int k = 1; k < 8; ++k) {
            float Pn[16];
            #pragma unroll
            for (int i = 0; i < 4; ++i) {
                #pragma unroll
                for (int j = 0; j < 4; ++j) {
                    float acc = P[i*4] * M[k][j];
                    acc = fmaf(P[i*4+1], M[k][4+j],  acc);
                    acc = fmaf(P[i*4+2], M[k][8+j],  acc);
                    acc = fmaf(P[i*4+3], M[k][12+j], acc);
                    Pn[i*4+j] = acc;
                }
            }
            #pragma unroll
            for (int e = 0; e < 16; ++e) P[e] = Pn[e];
        }
        float ss = 0.f;
        #pragma unroll
        for (int e = 0; e < 16; ++e) ss = fmaf(P[e], P[e], ss);
        const float rn = RSQ(ss);
        #pragma unroll
        for (int e = 0; e < 16; ++e)
            sP[s * 512 + e * 32 + bb] = P[e] * rn;
    }
    __syncthreads();

    // ---- phase 2: per-thread prefix / suffix vector scans ---------------
    float v0 = 1.f, v1 = 0.f, v2 = 0.f, v3 = 0.f;
    #pragma unroll 1
    for (int t = 0; t < s; ++t) {
        const float* pp = &sP[t * 512 + bb];
        const float p0  = pp[0],      p1  = pp[32],     p2  = pp[64],     p3  = pp[96];
        const float p4  = pp[128],    p5  = pp[160],    p6  = pp[192],    p7  = pp[224];
        const float p8  = pp[256],    p9  = pp[288],    p10 = pp[320],    p11 = pp[352];
        const float p12 = pp[384],    p13 = pp[416],    p14 = pp[448],    p15 = pp[480];
        const float w0 = v0*p0 + v1*p4 + v2*p8  + v3*p12;
        const float w1 = v0*p1 + v1*p5 + v2*p9  + v3*p13;
        const float w2 = v0*p2 + v1*p6 + v2*p10 + v3*p14;
        const float w3 = v0*p3 + v1*p7 + v2*p11 + v3*p15;
        const float rn = RSQ(w0*w0 + w1*w1 + w2*w2 + w3*w3);
        v0 = w0*rn; v1 = w1*rn; v2 = w2*rn; v3 = w3*rn;
    }
    float u0 = 1.f, u1 = 0.f, u2 = 0.f, u3 = 0.f;
    #pragma unroll 1
    for (int t = 7; t > s; --t) {
        const float* pp = &sP[t * 512 + bb];
        const float p0  = pp[0],      p1  = pp[32],     p2  = pp[64],     p3  = pp[96];
        const float p4  = pp[128],    p5  = pp[160],    p6  = pp[192],    p7  = pp[224];
        const float p8  = pp[256],    p9  = pp[288],    p10 = pp[320],    p11 = pp[352];
        const float p12 = pp[384],    p13 = pp[416],    p14 = pp[448],    p15 = pp[480];
        const float w0 = p0*u0  + p1*u1  + p2*u2  + p3*u3;
        const float w1 = p4*u0  + p5*u1  + p6*u2  + p7*u3;
        const float w2 = p8*u0  + p9*u1  + p10*u2 + p11*u3;
        const float w3 = p12*u0 + p13*u1 + p14*u2 + p15*u3;
        const float rn = RSQ(w0*w0 + w1*w1 + w2*w2 + w3*w3);
        u0 = w0*rn; u1 = w1*rn; u2 = w2*rn; u3 = w3*rn;
    }

    // ---- phase 3a: forward walk, store vl per site (cached M) ------------
    float vlA[8], vlB[8], vlC[8], vlD[8];
    {
        float a0 = v0, a1 = v1, a2 = v2, a3 = v3;
        #pragma unroll
        for (int k = 0; k < 8; ++k) {
            vlA[k] = a0; vlB[k] = a1; vlC[k] = a2; vlD[k] = a3;
            if (k == 7) break;
            const float t0 = a0*M[k][0] + a1*M[k][4] + a2*M[k][8]  + a3*M[k][12];
            const float t1 = a0*M[k][1] + a1*M[k][5] + a2*M[k][9]  + a3*M[k][13];
            const float t2 = a0*M[k][2] + a1*M[k][6] + a2*M[k][10] + a3*M[k][14];
            const float t3 = a0*M[k][3] + a1*M[k][7] + a2*M[k][11] + a3*M[k][15];
            a0 = t0; a1 = t1; a2 = t2; a3 = t3;
        }
    }

    // ---- phase 3b: backward walk + fused epilogue (B from LDS) -> sXY ----
    const float sc = scale[0];
    #pragma unroll
    for (int kk = 7; kk >= 0; --kk) {
        const int n = n0 + kk;

        const float arn = RSQ(u0*u0 + u1*u1 + u2*u2 + u3*u3);
        float aa0 = u0*arn, aa1 = u1*arn, aa2 = u2*arn, aa3 = u3*arn;
        if (n == 63) { aa0 = 1.f; aa1 = aa2 = aa3 = 0.f; }

        const float wn = RSQ(vlA[kk]*vlA[kk] + vlB[kk]*vlB[kk] +
                             vlC[kk]*vlC[kk] + vlD[kk]*vlD[kk]);
        float vv0 = vlA[kk]*wn, vv1 = vlB[kk]*wn, vv2 = vlC[kk]*wn, vv3 = vlD[kk]*wn;
        if (n == 0) { vv0 = 1.f; vv1 = vv2 = vv3 = 0.f; }

        const float vv[4] = {vv0, vv1, vv2, vv3};
        const float aa[4] = {aa0, aa1, aa2, aa3};
        const float4* Bq = &sB[n * 16];
        float H00 = 0.f, H01 = 0.f, H10 = 0.f, H11 = 0.f;
        #pragma unroll
        for (int half = 0; half < 2; ++half) {       // 8 float4 live at a time
            float4 bq[8];
            #pragma unroll
            for (int t = 0; t < 8; ++t) bq[t] = Bq[half * 8 + t];
            #pragma unroll
            for (int i2 = 0; i2 < 2; ++i2) {
                const int i = half * 2 + i2;
                #pragma unroll
                for (int l = 0; l < 4; ++l) {
                    const float  c = vv[i] * aa[l];
                    const float4 q = bq[i2 * 4 + l];
                    H00 = fmaf(c, q.x, H00);
                    H01 = fmaf(c, q.y, H01);
                    H10 = fmaf(c, q.z, H10);
                    H11 = fmaf(c, q.w, H11);
                }
            }
        }
        const float rh = sc * RSQ(H00*H00 + H01*H01 + H10*H10 + H11*H11);
        H00 *= rh; H01 *= rh; H10 *= rh; H11 *= rh;
        if (__builtin_isnan(H00)) H00 = 0.f;
        if (__builtin_isnan(H01)) H01 = 0.f;
        if (__builtin_isnan(H10)) H10 = 0.f;
        if (__builtin_isnan(H11)) H11 = 0.f;
        H00 = fmaxf(H00, 0.f); H01 = fmaxf(H01, 0.f);
        H10 = fmaxf(H10, 0.f); H11 = fmaxf(H11, 0.f);

        float2 yo;
        yo.x = fmaf(H01, xc[kk], H00 * xa[kk]);
        yo.y = fmaf(H11, xc[kk], H10 * xa[kk]);
        *(float2*)&sXY[bb * 130 + 2 * n] = yo;

        if (kk > 0) {   // u <- M[kk].u  (raw suffix for site n-1)
            const float t0 = M[kk][0]*u0  + M[kk][1]*u1  + M[kk][2]*u2  + M[kk][3]*u3;
            const float t1 = M[kk][4]*u0  + M[kk][5]*u1  + M[kk][6]*u2  + M[kk][7]*u3;
            const float t2 = M[kk][8]*u0  + M[kk][9]*u1  + M[kk][10]*u2 + M[kk][11]*u3;
            const float t3 = M[kk][12]*u0 + M[kk][13]*u1 + M[kk][14]*u2 + M[kk][15]*u3;
            u0 = t0; u1 = t1; u2 = t2; u3 = t3;
        }
    }
    __syncthreads();

    // ---- y out: fully coalesced float4 stores ----------------------------
    {
        float4* yg = (float4*)y + (size_t)blockIdx.x * 1024;
        #pragma unroll
        for (int it = 0; it < 4; ++it) {
            const int g = it * 256 + tid;
            const int c = g >> 5, f = (g & 31) * 4;
            const float2 a = *(const float2*)&sXY[c * 130 + f];
            const float2 b = *(const float2*)&sXY[c * 130 + f + 2];
            yg[g] = make_float4(a.x, a.y, b.x, b.y);
        }
    }
}

extern "C" void kernel_launch(void* const* d_in, const int* in_sizes, int n_in,
                              void* d_out, int out_size, void* d_ws, size_t ws_size,
                              hipStream_t stream) {
    const float* x     = (const float*)d_in[0];
    const float* A     = (const float*)d_in[1];
    const float* B     = (const float*)d_in[2];
    const float* scale = (const float*)d_in[3];
    float* yp = (float*)d_out;
    const int batch  = in_sizes[0] / 128;    // 16384
    const int blocks = batch / 32;           // 512 blocks x 256 threads
    tdvp_kernel<<<blocks, 256, 0, stream>>>(x, A, B, scale, yp);
}